// Round 1
// baseline (200.475 us; speedup 1.0000x reference)
//
#include <hip/hip_runtime.h>
#include <math.h>

#define TWO_PI 6.28318530717958647692f

// ---------------------------------------------------------------------------
// K1: cartesian -> polar sampling.  pf[b][c][a][r], one thread per element.
// x: [16][256][128][128] f32.  524288 threads.
// ---------------------------------------------------------------------------
__global__ __launch_bounds__(256) void k1_cart2polar(const float* __restrict__ x,
                                                     float* __restrict__ pf) {
    int t = blockIdx.x * 256 + threadIdx.x;   // < 524288
    int r = t & 7;
    int a = (t >> 3) & 15;
    int c = (t >> 7) & 255;
    int b = t >> 15;
    float theta = (TWO_PI * (float)a) / 16.0f;
    float rad   = ((float)r + 0.5f) / 8.0f * 64.0f;
    float ys = 63.5f + rad * sinf(theta);
    float xs = 63.5f + rad * cosf(theta);
    float y0 = floorf(ys), x0 = floorf(xs);
    float wy = ys - y0,    wx = xs - x0;
    int y0i = min(max((int)y0, 0), 127);
    int y1i = min(max((int)y0 + 1, 0), 127);
    int x0i = min(max((int)x0, 0), 127);
    int x1i = min(max((int)x0 + 1, 0), 127);
    const float* img = x + ((size_t)(b * 256 + c) << 14);
    float v00 = img[y0i * 128 + x0i];
    float v01 = img[y0i * 128 + x1i];
    float v10 = img[y1i * 128 + x0i];
    float v11 = img[y1i * 128 + x1i];
    float v = v00 * (1.0f - wy) * (1.0f - wx) + v01 * (1.0f - wy) * wx
            + v10 * wy * (1.0f - wx)          + v11 * wy * wx;
    float valid = (ys >= 0.0f && ys <= 127.0f && xs >= 0.0f && xs <= 127.0f) ? 1.0f : 0.0f;
    pf[t] = v * valid;
}

// ---------------------------------------------------------------------------
// K2: grouped 3x3 conv over (A=16, R=8), zero-pad 1, groups=4.
// Output written TRANSPOSED: pp_t[b][bin][oc]  (bin = a*8+r) so the next
// kernel's channel reduction is over contiguous memory.
// grid = 512 (b*32 + g*8 + ot), block = 128 (one thread per bin).
// Each block computes 8 output channels (oc = g*64 + ot*8 .. +7).
// ---------------------------------------------------------------------------
__global__ __launch_bounds__(128) void k2_conv(const float* __restrict__ pf,
                                               const float* __restrict__ w_polar,
                                               const float* __restrict__ b_polar,
                                               float* __restrict__ pp_t) {
    // padded tile: [64][18][10] (a+1, r+1 interior), zero halo
    __shared__ __align__(16) float pfs[64 * 180];
    int bid = blockIdx.x;
    int b  = bid >> 5;
    int g  = (bid >> 3) & 3;
    int ot = bid & 7;
    int tid = threadIdx.x;   // 0..127
    for (int i = tid; i < 64 * 180; i += 128) pfs[i] = 0.0f;
    __syncthreads();
    const float* src = pf + ((size_t)(b * 256 + g * 64) << 7);
    for (int i = tid; i < 8192; i += 128) {
        int ic = i >> 7, bin = i & 127;
        int a = bin >> 3, r = bin & 7;
        pfs[ic * 180 + (a + 1) * 10 + (r + 1)] = src[i];
    }
    __syncthreads();

    int a = tid >> 3, r = tid & 7;
    int oc0 = g * 64 + ot * 8;
    float acc[8];
    #pragma unroll
    for (int j = 0; j < 8; ++j) acc[j] = b_polar[oc0 + j];

    for (int ic = 0; ic < 64; ++ic) {
        float v[9];
        const float* base = pfs + ic * 180 + a * 10 + r;  // (a-1+1)*10 + (r-1+1)
        #pragma unroll
        for (int dh = 0; dh < 3; ++dh)
            #pragma unroll
            for (int dw = 0; dw < 3; ++dw)
                v[dh * 3 + dw] = base[dh * 10 + dw];
        #pragma unroll
        for (int j = 0; j < 8; ++j) {
            const float* wp = w_polar + ((size_t)(oc0 + j) * 64 + (size_t)ic) * 9;
            acc[j] += wp[0]*v[0] + wp[1]*v[1] + wp[2]*v[2]
                    + wp[3]*v[3] + wp[4]*v[4] + wp[5]*v[5]
                    + wp[6]*v[6] + wp[7]*v[7] + wp[8]*v[8];
        }
    }
    float* dst = pp_t + ((size_t)((b << 7) + tid)) * 256 + oc0;
    #pragma unroll
    for (int j = 0; j < 8; ++j) dst[j] = acc[j];
}

// ---------------------------------------------------------------------------
// K3: channel projection q[b][bin][o] = sum_c w_attn1[o][c] * pp_t[b][bin][c]
// grid = 512, block = 256; thread n: o = n&63 (lane), bin/b wave-uniform.
// W1 staged transposed [c][o] in LDS -> conflict-free reads.
// ---------------------------------------------------------------------------
__global__ __launch_bounds__(256) void k3_proj(const float* __restrict__ pp_t,
                                               const float* __restrict__ w_attn1,
                                               float* __restrict__ q) {
    __shared__ __align__(16) float wl[256 * 64];  // [c][o]
    int tid = threadIdx.x;
    for (int i = tid; i < 16384; i += 256) {
        int c = i >> 6, o = i & 63;
        wl[i] = w_attn1[o * 256 + c];
    }
    __syncthreads();
    int n = blockIdx.x * 256 + tid;     // < 131072
    int b   = n >> 13;
    int bin = (n >> 6) & 127;
    int o   = n & 63;
    const float4* pr4 = (const float4*)(pp_t + ((size_t)((b << 7) + bin)) * 256);
    float acc = 0.0f;
    #pragma unroll 8
    for (int c4 = 0; c4 < 64; ++c4) {
        float4 p = pr4[c4];
        int cb = c4 << 8;  // c4*4*64
        acc += wl[cb + o]        * p.x;
        acc += wl[cb + 64 + o]   * p.y;
        acc += wl[cb + 128 + o]  * p.z;
        acc += wl[cb + 192 + o]  * p.w;
    }
    q[n] = acc;
}

// ---------------------------------------------------------------------------
// K4a: attention map att[b][h][w].
// Per pixel: bilinear taps in (angle, radius) over q[b][*][o], relu MLP, sigmoid.
// grid = 128 (b*8 + tile), block = 256, 8 pixels per thread.
// ---------------------------------------------------------------------------
__global__ __launch_bounds__(256) void k4a_att(const float* __restrict__ q,
                                               const float* __restrict__ b_attn1,
                                               const float* __restrict__ w_attn2,
                                               const float* __restrict__ b_attn2,
                                               float* __restrict__ att) {
    __shared__ __align__(16) float qs[8192];   // [bin][o]
    __shared__ __align__(16) float b1s[64];
    __shared__ __align__(16) float w2s[64];
    int b    = blockIdx.x >> 3;
    int tile = blockIdx.x & 7;
    int tid  = threadIdx.x;
    const float* qb = q + ((size_t)b << 13);
    for (int i = tid; i < 8192; i += 256) qs[i] = qb[i];
    if (tid < 64) { b1s[tid] = b_attn1[tid]; w2s[tid] = w_attn2[tid]; }
    __syncthreads();
    float b2 = b_attn2[0];
    const float4* q4  = (const float4*)qs;
    const float4* b14 = (const float4*)b1s;
    const float4* w24 = (const float4*)w2s;

    for (int k = 0; k < 8; ++k) {
        int p = (tile << 11) + (k << 8) + tid;   // pixel within image
        int h = p >> 7, w = p & 127;
        float dy = (float)h - 63.5f;
        float dx = (float)w - 63.5f;
        float rr = sqrtf(dy * dy + dx * dx);
        float th = atan2f(dy, dx);
        if (th < 0.0f) th += TWO_PI;
        float aa = th / TWO_PI * 16.0f;          // same op order as reference
        float a0 = floorf(aa);
        float wa = aa - a0;
        int ia0 = ((int)a0) & 15;
        int ia1 = (ia0 + 1) & 15;
        float ri = rr / 64.0f * 8.0f - 0.5f;
        float r0 = floorf(ri);
        float wr = ri - r0;
        int ir0 = (int)fminf(fmaxf(r0, 0.0f), 7.0f);
        int ir1 = (int)fminf(fmaxf(r0 + 1.0f, 0.0f), 7.0f);
        float valid = (rr <= 64.0f) ? 1.0f : 0.0f;
        float w00 = valid * (1.0f - wa) * (1.0f - wr);
        float w01 = valid * (1.0f - wa) * wr;
        float w10 = valid * wa * (1.0f - wr);
        float w11 = valid * wa * wr;
        int b00 = (ia0 * 8 + ir0) << 4;
        int b01 = (ia0 * 8 + ir1) << 4;
        int b10 = (ia1 * 8 + ir0) << 4;
        int b11 = (ia1 * 8 + ir1) << 4;
        float acc = b2;
        #pragma unroll
        for (int i = 0; i < 16; ++i) {
            float4 v00 = q4[b00 + i], v01 = q4[b01 + i];
            float4 v10 = q4[b10 + i], v11 = q4[b11 + i];
            float4 bb = b14[i], ww = w24[i];
            float sx = w00 * v00.x + w01 * v01.x + w10 * v10.x + w11 * v11.x;
            float sy = w00 * v00.y + w01 * v01.y + w10 * v10.y + w11 * v11.y;
            float sz = w00 * v00.z + w01 * v01.z + w10 * v10.z + w11 * v11.z;
            float sw = w00 * v00.w + w01 * v01.w + w10 * v10.w + w11 * v11.w;
            acc += fmaxf(sx + bb.x, 0.0f) * ww.x;
            acc += fmaxf(sy + bb.y, 0.0f) * ww.y;
            acc += fmaxf(sz + bb.z, 0.0f) * ww.z;
            acc += fmaxf(sw + bb.w, 0.0f) * ww.w;
        }
        float attv = 1.0f / (1.0f + expf(-acc));
        att[((size_t)b << 14) + p] = attv;
    }
}

// ---------------------------------------------------------------------------
// K4b: out = x * att (broadcast over channels). Pure streaming, float4.
// 2048 blocks x 256 threads, grid-stride over 16,777,216 float4s.
// ---------------------------------------------------------------------------
__global__ __launch_bounds__(256) void k4b_mul(const float4* __restrict__ x4,
                                               const float* __restrict__ att,
                                               float4* __restrict__ out4) {
    const float4* att4 = (const float4*)att;
    int idx = blockIdx.x * 256 + threadIdx.x;
    int stride = gridDim.x * 256;
    for (int i = idx; i < 16777216; i += stride) {
        float4 xv = x4[i];
        float4 av = att4[((i >> 20) << 12) | (i & 4095)];
        out4[i] = make_float4(xv.x * av.x, xv.y * av.y, xv.z * av.z, xv.w * av.w);
    }
}

// ---------------------------------------------------------------------------
extern "C" void kernel_launch(void* const* d_in, const int* in_sizes, int n_in,
                              void* d_out, int out_size, void* d_ws, size_t ws_size,
                              hipStream_t stream) {
    const float* x       = (const float*)d_in[0];
    const float* w_polar = (const float*)d_in[1];
    const float* b_polar = (const float*)d_in[2];
    const float* w_attn1 = (const float*)d_in[3];
    const float* b_attn1 = (const float*)d_in[4];
    const float* w_attn2 = (const float*)d_in[5];
    const float* b_attn2 = (const float*)d_in[6];
    float* out = (float*)d_out;
    float* ws  = (float*)d_ws;

    float* pf   = ws;                 // 524288 f  (2 MB)   [b][c][a][r]
    float* pp_t = ws + 524288;        // 524288 f  (2 MB)   [b][bin][c]
    float* q    = ws + 1048576;       // 131072 f  (0.5 MB) [b][bin][o]
    float* att  = ws + 1179648;       // 262144 f  (1 MB)   [b][h][w]

    hipLaunchKernelGGL(k1_cart2polar, dim3(2048), dim3(256), 0, stream, x, pf);
    hipLaunchKernelGGL(k2_conv,       dim3(512),  dim3(128), 0, stream, pf, w_polar, b_polar, pp_t);
    hipLaunchKernelGGL(k3_proj,       dim3(512),  dim3(256), 0, stream, pp_t, w_attn1, q);
    hipLaunchKernelGGL(k4a_att,       dim3(128),  dim3(256), 0, stream, q, b_attn1, w_attn2, b_attn2, att);
    hipLaunchKernelGGL(k4b_mul,       dim3(2048), dim3(256), 0, stream,
                       (const float4*)x, att, (float4*)out);
}

// Round 2
// 180.007 us; speedup vs baseline: 1.1137x; 1.1137x over previous
//
#include <hip/hip_runtime.h>
#include <math.h>

#define TWO_PI 6.28318530717958647692f

// ---------------------------------------------------------------------------
// K1: cartesian -> polar sampling.  pf[b][c][a][r], one thread per element.
// ---------------------------------------------------------------------------
__global__ __launch_bounds__(256) void k1_cart2polar(const float* __restrict__ x,
                                                     float* __restrict__ pf) {
    int t = blockIdx.x * 256 + threadIdx.x;   // < 524288
    int r = t & 7;
    int a = (t >> 3) & 15;
    int c = (t >> 7) & 255;
    int b = t >> 15;
    float theta = (TWO_PI * (float)a) / 16.0f;
    float rad   = ((float)r + 0.5f) / 8.0f * 64.0f;
    float ys = 63.5f + rad * sinf(theta);
    float xs = 63.5f + rad * cosf(theta);
    float y0 = floorf(ys), x0 = floorf(xs);
    float wy = ys - y0,    wx = xs - x0;
    int y0i = min(max((int)y0, 0), 127);
    int y1i = min(max((int)y0 + 1, 0), 127);
    int x0i = min(max((int)x0, 0), 127);
    int x1i = min(max((int)x0 + 1, 0), 127);
    const float* img = x + ((size_t)(b * 256 + c) << 14);
    float v00 = img[y0i * 128 + x0i];
    float v01 = img[y0i * 128 + x1i];
    float v10 = img[y1i * 128 + x0i];
    float v11 = img[y1i * 128 + x1i];
    float v = v00 * (1.0f - wy) * (1.0f - wx) + v01 * (1.0f - wy) * wx
            + v10 * wy * (1.0f - wx)          + v11 * wy * wx;
    float valid = (ys >= 0.0f && ys <= 127.0f && xs >= 0.0f && xs <= 127.0f) ? 1.0f : 0.0f;
    pf[t] = v * valid;
}

// ---------------------------------------------------------------------------
// K2: grouped 3x3 conv over (A=16, R=8), zero-pad 1, groups=4.
// Output transposed: pp_t[b][bin][oc].
// ---------------------------------------------------------------------------
__global__ __launch_bounds__(128) void k2_conv(const float* __restrict__ pf,
                                               const float* __restrict__ w_polar,
                                               const float* __restrict__ b_polar,
                                               float* __restrict__ pp_t) {
    __shared__ __align__(16) float pfs[64 * 180];
    int bid = blockIdx.x;
    int b  = bid >> 5;
    int g  = (bid >> 3) & 3;
    int ot = bid & 7;
    int tid = threadIdx.x;
    for (int i = tid; i < 64 * 180; i += 128) pfs[i] = 0.0f;
    __syncthreads();
    const float* src = pf + ((size_t)(b * 256 + g * 64) << 7);
    for (int i = tid; i < 8192; i += 128) {
        int ic = i >> 7, bin = i & 127;
        int a = bin >> 3, r = bin & 7;
        pfs[ic * 180 + (a + 1) * 10 + (r + 1)] = src[i];
    }
    __syncthreads();

    int a = tid >> 3, r = tid & 7;
    int oc0 = g * 64 + ot * 8;
    float acc[8];
    #pragma unroll
    for (int j = 0; j < 8; ++j) acc[j] = b_polar[oc0 + j];

    for (int ic = 0; ic < 64; ++ic) {
        float v[9];
        const float* base = pfs + ic * 180 + a * 10 + r;
        #pragma unroll
        for (int dh = 0; dh < 3; ++dh)
            #pragma unroll
            for (int dw = 0; dw < 3; ++dw)
                v[dh * 3 + dw] = base[dh * 10 + dw];
        #pragma unroll
        for (int j = 0; j < 8; ++j) {
            const float* wp = w_polar + ((size_t)(oc0 + j) * 64 + (size_t)ic) * 9;
            acc[j] += wp[0]*v[0] + wp[1]*v[1] + wp[2]*v[2]
                    + wp[3]*v[3] + wp[4]*v[4] + wp[5]*v[5]
                    + wp[6]*v[6] + wp[7]*v[7] + wp[8]*v[8];
        }
    }
    float* dst = pp_t + ((size_t)((b << 7) + tid)) * 256 + oc0;
    #pragma unroll
    for (int j = 0; j < 8; ++j) dst[j] = acc[j];
}

// ---------------------------------------------------------------------------
// K3: q[b][bin][o] = sum_c w_attn1[o][c] * pp_t[b][bin][c]
// W1 staged with COALESCED global reads + XOR-swizzled LDS layout:
//   logical wl[c][o] stored at (c<<6) + (o ^ (c&31))  -> conflict-free both ways.
// grid = 512, block = 256; lane = o, wave-uniform (b,bin).
// ---------------------------------------------------------------------------
__global__ __launch_bounds__(256) void k3_proj(const float* __restrict__ pp_t,
                                               const float* __restrict__ w_attn1,
                                               float* __restrict__ q) {
    __shared__ __align__(16) float wl[16384];
    int tid = threadIdx.x;
    for (int i = tid; i < 16384; i += 256) {       // i = o*256 + c (flat w_attn1)
        int o = i >> 8, c = i & 255;
        wl[(c << 6) + (o ^ (c & 31))] = w_attn1[i];
    }
    __syncthreads();
    int n = blockIdx.x * 256 + tid;     // < 131072
    int b   = n >> 13;
    int bin = (n >> 6) & 127;
    int o   = n & 63;
    const float4* pr4 = (const float4*)(pp_t + ((size_t)((b << 7) + bin)) * 256);
    float acc = 0.0f;
    #pragma unroll 8
    for (int c4 = 0; c4 < 64; ++c4) {
        float4 p = pr4[c4];
        int c = c4 << 2;
        acc += wl[( c      << 6) + (o ^ ( c      & 31))] * p.x;
        acc += wl[((c + 1) << 6) + (o ^ ((c + 1) & 31))] * p.y;
        acc += wl[((c + 2) << 6) + (o ^ ((c + 2) & 31))] * p.z;
        acc += wl[((c + 3) << 6) + (o ^ ((c + 3) & 31))] * p.w;
    }
    q[n] = acc;
}

// ---------------------------------------------------------------------------
// K4a: attention map att[b][h][w]. 1024 blocks (64 per batch), 1 px/thread.
// q staged in LDS with swizzled layout base(ia,ir) = ia*556 + ir*68 floats
// -> bank = (12*ia + 4*ir + dword) mod 32: both angle & radius spread banks.
// ---------------------------------------------------------------------------
__global__ __launch_bounds__(256) void k4a_att(const float* __restrict__ q,
                                               const float* __restrict__ b_attn1,
                                               const float* __restrict__ w_attn2,
                                               const float* __restrict__ b_attn2,
                                               float* __restrict__ att) {
    __shared__ __align__(16) float qs[8896];   // swizzled [ia][ir][o]
    __shared__ __align__(16) float b1s[64];
    __shared__ __align__(16) float w2s[64];
    int b    = blockIdx.x >> 6;
    int tile = blockIdx.x & 63;
    int tid  = threadIdx.x;
    const float* qb = q + ((size_t)b << 13);
    for (int i = tid; i < 8192; i += 256) {
        int bin = i >> 6, o = i & 63;
        qs[(bin >> 3) * 556 + (bin & 7) * 68 + o] = qb[i];
    }
    if (tid < 64) { b1s[tid] = b_attn1[tid]; w2s[tid] = w_attn2[tid]; }
    __syncthreads();
    float b2 = b_attn2[0];
    const float4* q4  = (const float4*)qs;
    const float4* b14 = (const float4*)b1s;
    const float4* w24 = (const float4*)w2s;

    int p = (tile << 8) + tid;               // pixel within image
    int h = p >> 7, w = p & 127;
    float dy = (float)h - 63.5f;
    float dx = (float)w - 63.5f;
    float rr = sqrtf(dy * dy + dx * dx);
    float th = atan2f(dy, dx);
    if (th < 0.0f) th += TWO_PI;
    float aa = th / TWO_PI * 16.0f;
    float a0 = floorf(aa);
    float wa = aa - a0;
    int ia0 = ((int)a0) & 15;
    int ia1 = (ia0 + 1) & 15;
    float ri = rr / 64.0f * 8.0f - 0.5f;
    float r0 = floorf(ri);
    float wr = ri - r0;
    int ir0 = (int)fminf(fmaxf(r0, 0.0f), 7.0f);
    int ir1 = (int)fminf(fmaxf(r0 + 1.0f, 0.0f), 7.0f);
    float valid = (rr <= 64.0f) ? 1.0f : 0.0f;
    float w00 = valid * (1.0f - wa) * (1.0f - wr);
    float w01 = valid * (1.0f - wa) * wr;
    float w10 = valid * wa * (1.0f - wr);
    float w11 = valid * wa * wr;
    int t00 = ia0 * 139 + ir0 * 17;          // float4 indices
    int t01 = ia0 * 139 + ir1 * 17;
    int t10 = ia1 * 139 + ir0 * 17;
    int t11 = ia1 * 139 + ir1 * 17;
    float acc = b2;
    #pragma unroll
    for (int i = 0; i < 16; ++i) {
        float4 v00 = q4[t00 + i], v01 = q4[t01 + i];
        float4 v10 = q4[t10 + i], v11 = q4[t11 + i];
        float4 bb = b14[i], ww = w24[i];
        float sx = w00 * v00.x + w01 * v01.x + w10 * v10.x + w11 * v11.x;
        float sy = w00 * v00.y + w01 * v01.y + w10 * v10.y + w11 * v11.y;
        float sz = w00 * v00.z + w01 * v01.z + w10 * v10.z + w11 * v11.z;
        float sw = w00 * v00.w + w01 * v01.w + w10 * v10.w + w11 * v11.w;
        acc += fmaxf(sx + bb.x, 0.0f) * ww.x;
        acc += fmaxf(sy + bb.y, 0.0f) * ww.y;
        acc += fmaxf(sz + bb.z, 0.0f) * ww.z;
        acc += fmaxf(sw + bb.w, 0.0f) * ww.w;
    }
    float attv = 1.0f / (1.0f + expf(-acc));
    att[((size_t)b << 14) + p] = attv;
}

// ---------------------------------------------------------------------------
// K4b: out = x * att (broadcast over channels). Pure streaming, float4.
// ---------------------------------------------------------------------------
__global__ __launch_bounds__(256) void k4b_mul(const float4* __restrict__ x4,
                                               const float* __restrict__ att,
                                               float4* __restrict__ out4) {
    const float4* att4 = (const float4*)att;
    int idx = blockIdx.x * 256 + threadIdx.x;
    int stride = gridDim.x * 256;
    for (int i = idx; i < 16777216; i += stride) {
        float4 xv = x4[i];
        float4 av = att4[((i >> 20) << 12) | (i & 4095)];
        out4[i] = make_float4(xv.x * av.x, xv.y * av.y, xv.z * av.z, xv.w * av.w);
    }
}

// ---------------------------------------------------------------------------
extern "C" void kernel_launch(void* const* d_in, const int* in_sizes, int n_in,
                              void* d_out, int out_size, void* d_ws, size_t ws_size,
                              hipStream_t stream) {
    const float* x       = (const float*)d_in[0];
    const float* w_polar = (const float*)d_in[1];
    const float* b_polar = (const float*)d_in[2];
    const float* w_attn1 = (const float*)d_in[3];
    const float* b_attn1 = (const float*)d_in[4];
    const float* w_attn2 = (const float*)d_in[5];
    const float* b_attn2 = (const float*)d_in[6];
    float* out = (float*)d_out;
    float* ws  = (float*)d_ws;

    float* pf   = ws;                 // 524288 f  [b][c][a][r]
    float* pp_t = ws + 524288;        // 524288 f  [b][bin][c]
    float* q    = ws + 1048576;       // 131072 f  [b][bin][o]
    float* att  = ws + 1179648;       // 262144 f  [b][h][w]

    hipLaunchKernelGGL(k1_cart2polar, dim3(2048), dim3(256), 0, stream, x, pf);
    hipLaunchKernelGGL(k2_conv,       dim3(512),  dim3(128), 0, stream, pf, w_polar, b_polar, pp_t);
    hipLaunchKernelGGL(k3_proj,       dim3(512),  dim3(256), 0, stream, pp_t, w_attn1, q);
    hipLaunchKernelGGL(k4a_att,       dim3(1024), dim3(256), 0, stream, q, b_attn1, w_attn2, b_attn2, att);
    hipLaunchKernelGGL(k4b_mul,       dim3(2048), dim3(256), 0, stream,
                       (const float4*)x, att, (float4*)out);
}

// Round 3
// 172.018 us; speedup vs baseline: 1.1654x; 1.0464x over previous
//
#include <hip/hip_runtime.h>
#include <math.h>

#define TWO_PI 6.28318530717958647692f

typedef float f4 __attribute__((ext_vector_type(4)));

// ---------------------------------------------------------------------------
// K1: cartesian -> polar sampling.  pf[b][c][a][r], one thread per element.
// Only 128 distinct sample points exist -> build tap table (SoA, conflict-free
// LDS) once per block; threads do 4 gathers + 4 FMAs.
// ---------------------------------------------------------------------------
__global__ __launch_bounds__(256) void k1_cart2polar(const float* __restrict__ x,
                                                     float* __restrict__ pf) {
    __shared__ float w00s[128], w01s[128], w10s[128], w11s[128];
    __shared__ int   o00s[128], o01s[128], o10s[128], o11s[128];
    int tid = threadIdx.x;
    if (tid < 128) {
        int a = tid >> 3, r = tid & 7;
        float theta = (TWO_PI * (float)a) / 16.0f;
        float rad   = ((float)r + 0.5f) / 8.0f * 64.0f;
        float ys = 63.5f + rad * sinf(theta);
        float xs = 63.5f + rad * cosf(theta);
        float y0 = floorf(ys), x0 = floorf(xs);
        float wy = ys - y0,    wx = xs - x0;
        int y0i = min(max((int)y0, 0), 127);
        int y1i = min(max((int)y0 + 1, 0), 127);
        int x0i = min(max((int)x0, 0), 127);
        int x1i = min(max((int)x0 + 1, 0), 127);
        float valid = (ys >= 0.0f && ys <= 127.0f && xs >= 0.0f && xs <= 127.0f) ? 1.0f : 0.0f;
        w00s[tid] = valid * (1.0f - wy) * (1.0f - wx);
        w01s[tid] = valid * (1.0f - wy) * wx;
        w10s[tid] = valid * wy * (1.0f - wx);
        w11s[tid] = valid * wy * wx;
        o00s[tid] = y0i * 128 + x0i;
        o01s[tid] = y0i * 128 + x1i;
        o10s[tid] = y1i * 128 + x0i;
        o11s[tid] = y1i * 128 + x1i;
    }
    __syncthreads();
    int t = blockIdx.x * 256 + tid;     // < 524288
    int bin = t & 127;
    int img = t >> 7;                   // b*256 + c
    const float* ib = x + ((size_t)img << 14);
    float v = ib[o00s[bin]] * w00s[bin]
            + ib[o01s[bin]] * w01s[bin]
            + ib[o10s[bin]] * w10s[bin]
            + ib[o11s[bin]] * w11s[bin];
    pf[t] = v;
}

// ---------------------------------------------------------------------------
// K2: grouped 3x3 conv over (A=16, R=8), zero-pad 1, groups=4.
// Output transposed: pp_t[b][bin][oc].
// 256 threads: ic-loop split across two halves (ic 0..31 / 32..63), LDS-reduce.
// ---------------------------------------------------------------------------
__global__ __launch_bounds__(256) void k2_conv(const float* __restrict__ pf,
                                               const float* __restrict__ w_polar,
                                               const float* __restrict__ b_polar,
                                               float* __restrict__ pp_t) {
    __shared__ __align__(16) float pfs[64 * 180];
    __shared__ __align__(16) float red[128 * 8];
    int bid = blockIdx.x;               // 512
    int b  = bid >> 5;
    int g  = (bid >> 3) & 3;
    int ot = bid & 7;
    int tid = threadIdx.x;
    for (int i = tid; i < 64 * 180; i += 256) pfs[i] = 0.0f;
    __syncthreads();
    const float* src = pf + ((size_t)(b * 256 + g * 64) << 7);
    for (int i = tid; i < 8192; i += 256) {
        int ic = i >> 7, bin = i & 127;
        pfs[ic * 180 + ((bin >> 3) + 1) * 10 + (bin & 7) + 1] = src[i];
    }
    __syncthreads();

    int half = tid >> 7;
    int bt   = tid & 127;
    int a = bt >> 3, r = bt & 7;
    int oc0 = g * 64 + ot * 8;
    float acc[8];
    #pragma unroll
    for (int j = 0; j < 8; ++j) acc[j] = 0.0f;

    const float* wbase = w_polar + (size_t)oc0 * 576 + half * 288;  // + j*576 + ic*9
    const float* pbase = pfs + half * 32 * 180 + a * 10 + r;
    for (int ic = 0; ic < 32; ++ic) {
        float v[9];
        const float* base = pbase + ic * 180;
        #pragma unroll
        for (int dh = 0; dh < 3; ++dh)
            #pragma unroll
            for (int dw = 0; dw < 3; ++dw)
                v[dh * 3 + dw] = base[dh * 10 + dw];
        #pragma unroll
        for (int j = 0; j < 8; ++j) {
            const float* wp = wbase + j * 576 + ic * 9;
            acc[j] += wp[0]*v[0] + wp[1]*v[1] + wp[2]*v[2]
                    + wp[3]*v[3] + wp[4]*v[4] + wp[5]*v[5]
                    + wp[6]*v[6] + wp[7]*v[7] + wp[8]*v[8];
        }
    }
    if (half) {
        #pragma unroll
        for (int j = 0; j < 8; ++j) red[bt * 8 + j] = acc[j];
    }
    __syncthreads();
    if (!half) {
        float* dst = pp_t + ((size_t)((b << 7) + bt)) * 256 + oc0;
        #pragma unroll
        for (int j = 0; j < 8; ++j)
            dst[j] = acc[j] + red[bt * 8 + j] + b_polar[oc0 + j];
    }
}

// ---------------------------------------------------------------------------
// K3: q[b][bin][o] = sum_c w_attn1[o][c] * pp_t[b][bin][c]
// Coalesced global staging + XOR-swizzled LDS, conflict-free both ways.
// ---------------------------------------------------------------------------
__global__ __launch_bounds__(256) void k3_proj(const float* __restrict__ pp_t,
                                               const float* __restrict__ w_attn1,
                                               float* __restrict__ q) {
    __shared__ __align__(16) float wl[16384];
    int tid = threadIdx.x;
    for (int i = tid; i < 16384; i += 256) {       // i = o*256 + c
        int o = i >> 8, c = i & 255;
        wl[(c << 6) + (o ^ (c & 31))] = w_attn1[i];
    }
    __syncthreads();
    int n = blockIdx.x * 256 + tid;     // < 131072
    int b   = n >> 13;
    int bin = (n >> 6) & 127;
    int o   = n & 63;
    const float4* pr4 = (const float4*)(pp_t + ((size_t)((b << 7) + bin)) * 256);
    float acc = 0.0f;
    #pragma unroll 8
    for (int c4 = 0; c4 < 64; ++c4) {
        float4 p = pr4[c4];
        int c = c4 << 2;
        acc += wl[( c      << 6) + (o ^ ( c      & 31))] * p.x;
        acc += wl[((c + 1) << 6) + (o ^ ((c + 1) & 31))] * p.y;
        acc += wl[((c + 2) << 6) + (o ^ ((c + 2) & 31))] * p.z;
        acc += wl[((c + 3) << 6) + (o ^ ((c + 3) & 31))] * p.w;
    }
    q[n] = acc;
}

// ---------------------------------------------------------------------------
// K4a: attention map att[b][h][w]. 1024 blocks, 1 px/thread.
// q staged swizzled: base(ia,ir) = ia*556 + ir*68 floats.
// ---------------------------------------------------------------------------
__global__ __launch_bounds__(256) void k4a_att(const float* __restrict__ q,
                                               const float* __restrict__ b_attn1,
                                               const float* __restrict__ w_attn2,
                                               const float* __restrict__ b_attn2,
                                               float* __restrict__ att) {
    __shared__ __align__(16) float qs[8896];
    __shared__ __align__(16) float b1s[64];
    __shared__ __align__(16) float w2s[64];
    int b    = blockIdx.x >> 6;
    int tile = blockIdx.x & 63;
    int tid  = threadIdx.x;
    const float* qb = q + ((size_t)b << 13);
    for (int i = tid; i < 8192; i += 256) {
        int bin = i >> 6, o = i & 63;
        qs[(bin >> 3) * 556 + (bin & 7) * 68 + o] = qb[i];
    }
    if (tid < 64) { b1s[tid] = b_attn1[tid]; w2s[tid] = w_attn2[tid]; }
    __syncthreads();
    float b2 = b_attn2[0];
    const float4* q4  = (const float4*)qs;
    const float4* b14 = (const float4*)b1s;
    const float4* w24 = (const float4*)w2s;

    int p = (tile << 8) + tid;
    int h = p >> 7, w = p & 127;
    float dy = (float)h - 63.5f;
    float dx = (float)w - 63.5f;
    float rr = sqrtf(dy * dy + dx * dx);
    float th = atan2f(dy, dx);
    if (th < 0.0f) th += TWO_PI;
    float aa = th / TWO_PI * 16.0f;
    float a0 = floorf(aa);
    float wa = aa - a0;
    int ia0 = ((int)a0) & 15;
    int ia1 = (ia0 + 1) & 15;
    float ri = rr / 64.0f * 8.0f - 0.5f;
    float r0 = floorf(ri);
    float wr = ri - r0;
    int ir0 = (int)fminf(fmaxf(r0, 0.0f), 7.0f);
    int ir1 = (int)fminf(fmaxf(r0 + 1.0f, 0.0f), 7.0f);
    float valid = (rr <= 64.0f) ? 1.0f : 0.0f;
    float w00 = valid * (1.0f - wa) * (1.0f - wr);
    float w01 = valid * (1.0f - wa) * wr;
    float w10 = valid * wa * (1.0f - wr);
    float w11 = valid * wa * wr;
    int t00 = ia0 * 139 + ir0 * 17;
    int t01 = ia0 * 139 + ir1 * 17;
    int t10 = ia1 * 139 + ir0 * 17;
    int t11 = ia1 * 139 + ir1 * 17;
    float acc = b2;
    #pragma unroll
    for (int i = 0; i < 16; ++i) {
        float4 v00 = q4[t00 + i], v01 = q4[t01 + i];
        float4 v10 = q4[t10 + i], v11 = q4[t11 + i];
        float4 bb = b14[i], ww = w24[i];
        float sx = w00 * v00.x + w01 * v01.x + w10 * v10.x + w11 * v11.x;
        float sy = w00 * v00.y + w01 * v01.y + w10 * v10.y + w11 * v11.y;
        float sz = w00 * v00.z + w01 * v01.z + w10 * v10.z + w11 * v11.z;
        float sw = w00 * v00.w + w01 * v01.w + w10 * v10.w + w11 * v11.w;
        acc += fmaxf(sx + bb.x, 0.0f) * ww.x;
        acc += fmaxf(sy + bb.y, 0.0f) * ww.y;
        acc += fmaxf(sz + bb.z, 0.0f) * ww.z;
        acc += fmaxf(sw + bb.w, 0.0f) * ww.w;
    }
    float attv = 1.0f / (1.0f + __expf(-acc));
    att[((size_t)b << 14) + p] = attv;
}

// ---------------------------------------------------------------------------
// K4b: out = x * att. Nontemporal on the two 268 MB streams; att stays cached.
// ---------------------------------------------------------------------------
__global__ __launch_bounds__(256) void k4b_mul(const f4* __restrict__ x4,
                                               const float* __restrict__ att,
                                               f4* __restrict__ out4) {
    const f4* att4 = (const f4*)att;
    int idx = blockIdx.x * 256 + threadIdx.x;
    int stride = gridDim.x * 256;
    for (int i = idx; i < 16777216; i += stride) {
        f4 xv = __builtin_nontemporal_load(&x4[i]);
        f4 av = att4[((i >> 20) << 12) | (i & 4095)];
        __builtin_nontemporal_store(xv * av, &out4[i]);
    }
}

// ---------------------------------------------------------------------------
extern "C" void kernel_launch(void* const* d_in, const int* in_sizes, int n_in,
                              void* d_out, int out_size, void* d_ws, size_t ws_size,
                              hipStream_t stream) {
    const float* x       = (const float*)d_in[0];
    const float* w_polar = (const float*)d_in[1];
    const float* b_polar = (const float*)d_in[2];
    const float* w_attn1 = (const float*)d_in[3];
    const float* b_attn1 = (const float*)d_in[4];
    const float* w_attn2 = (const float*)d_in[5];
    const float* b_attn2 = (const float*)d_in[6];
    float* out = (float*)d_out;
    float* ws  = (float*)d_ws;

    float* pf   = ws;                 // 524288 f  [b][c][a][r]
    float* pp_t = ws + 524288;        // 524288 f  [b][bin][c]
    float* q    = ws + 1048576;       // 131072 f  [b][bin][o]
    float* att  = ws + 1179648;       // 262144 f  [b][h][w]

    hipLaunchKernelGGL(k1_cart2polar, dim3(2048), dim3(256), 0, stream, x, pf);
    hipLaunchKernelGGL(k2_conv,       dim3(512),  dim3(256), 0, stream, pf, w_polar, b_polar, pp_t);
    hipLaunchKernelGGL(k3_proj,       dim3(512),  dim3(256), 0, stream, pp_t, w_attn1, q);
    hipLaunchKernelGGL(k4a_att,       dim3(1024), dim3(256), 0, stream, q, b_attn1, w_attn2, b_attn2, att);
    hipLaunchKernelGGL(k4b_mul,       dim3(2048), dim3(256), 0, stream,
                       (const f4*)x, att, (f4*)out);
}